// Round 23
// baseline (56.792 us; speedup 1.0000x reference)
//
#include <hip/hip_runtime.h>
#include <hip/hip_bf16.h>
#include <stdint.h>

#define NB 8192
#define DK 256
// gamma * log2(e): epilogue uses native exp2
#define GSCALE 14.426950408889634f

typedef short short8 __attribute__((ext_vector_type(8)));
typedef float f32x4 __attribute__((ext_vector_type(4)));

__device__ __forceinline__ unsigned short f32_to_bf16(float f) {
  uint32_t u = __builtin_bit_cast(uint32_t, f);
  u += 0x7FFFu + ((u >> 16) & 1u);   // RNE
  return (unsigned short)(u >> 16);
}

// Normalize (gamma*log2e folded into e side) AND write in PACKED MFMA-fragment
// layout (16x16x32 shape): fragment (row-panel p = r>>4, ks = k>>5) is a
// contiguous 1-KB chunk; lane l owns bytes l*16..+16.
// packed_byte(r,k) = (r>>4)*8192 + (k>>5)*1024 + ((k>>3)&3)*256 + (r&15)*16 + (k&7)*2.
// Blocks 0..15 also zero d_out (replaces hipMemsetAsync).
__global__ __launch_bounds__(256) void normpack_kernel(const float* __restrict__ e,
                                                       const float* __restrict__ v,
                                                       unsigned short* __restrict__ apk,
                                                       unsigned short* __restrict__ vpk,
                                                       float* __restrict__ out) {
  if (blockIdx.x < 16) {
    float4 z = {0.f, 0.f, 0.f, 0.f};
    reinterpret_cast<float4*>(out)[blockIdx.x * 256 + threadIdx.x] = z;
  }
  int wave = threadIdx.x >> 6;
  int lane = threadIdx.x & 63;
  int row = blockIdx.x * 4 + wave;          // 0..16383
  const float* src;
  unsigned short* dstbase;
  float mul;
  if (row < NB) {
    src = e + (size_t)row * DK; dstbase = apk; mul = GSCALE;
  } else {
    row -= NB;
    src = v + (size_t)row * DK; dstbase = vpk; mul = 1.0f;
  }
  float4 x = reinterpret_cast<const float4*>(src)[lane];   // k = 4*lane .. +3
  float ss = x.x * x.x + x.y * x.y + x.z * x.z + x.w * x.w;
  #pragma unroll
  for (int off = 32; off >= 1; off >>= 1) ss += __shfl_xor(ss, off);
  float s = mul / fmaxf(sqrtf(ss), 1e-8f);
  ushort4 o;
  o.x = f32_to_bf16(x.x * s);
  o.y = f32_to_bf16(x.y * s);
  o.z = f32_to_bf16(x.z * s);
  o.w = f32_to_bf16(x.w * s);
  size_t off = (size_t)(row >> 4) * 8192 + (size_t)(lane >> 3) * 1024 +
               ((lane >> 1) & 3) * 256 + (row & 15) * 16 + (lane & 1) * 8;
  *reinterpret_cast<ushort4*>((char*)dstbase + off) = o;
}

// R19/R22 (best verified: 55.8-56.0us) with the K-LOOP INTERIOR register
// footprint cut to cross the 4-waves/SIMD boundary NATURALLY (no forcing
// cap -- R20's lesson; no epilogue change -- R21's lesson):
//   (1) B ring 3->2 (S[2][4], -16 regs; R13-proven shape),
//   (2) af[4] -> af[2] x 2 sub-phases (-8 regs, same op counts).
// Target: acc 64 AGPR + ~60-64 arch = ~124-128 unified -> 4 waves/SIMD.
// Everything else byte-identical: 64x512 block, 2 col-tiles, per-tile ring
// re-init, tile-1 fill under tile-0's pure-VALU/LDS epilogue, counted
// vmcnt(8) prologue, setprio, no in-loop barriers, rp[4][4] carry, tail
// atomic burst.
__global__ __launch_bounds__(256, 3) void score_kernel(const unsigned short* __restrict__ apk,
                                                       const unsigned short* __restrict__ vpk,
                                                       float* __restrict__ out) {
  __shared__ unsigned short As[16384];      // 32 KB packed A panel
  __shared__ float colsum[512];             // 2 KB
  __shared__ float rowsum[4][64];           // 1 KB

  const int tid = threadIdx.x;
  const int w = tid >> 6;          // 0..3 (64-col group within each tile)
  const int lane = tid & 63;
  const int lo16 = lane & 15;
  const int q4 = lane >> 4;        // 0..3

  // 2048 blocks: xcd = id&7; 2 colblks per XCD -> B hot-set 512 KB, L2-resident;
  // consecutive t walk rowblks within a colblk (A panel L2-reused).
  int id = blockIdx.x;
  int xcd = id & 7;
  int t = id >> 3;                      // 0..255
  int colblk = (xcd << 1) | (t & 1);    // 0..15  (512-col strip)
  int rowblk = t >> 1;                  // 0..127 (64-row panel)

  // ---- Stage A panel: 32 KB, pure linear copy of packed fragments ----
  const char* aP = (const char*)apk + (size_t)rowblk * 32768;
  #pragma unroll
  for (int u = 0; u < 8; ++u) {
    int chunk = w * 8 + u;                     // 0..31 (1-KB fragments)
    const char* src = aP + chunk * 1024 + lane * 16;
    unsigned short* dst = &As[chunk * 512];
    __builtin_amdgcn_global_load_lds((const __attribute__((address_space(1))) uint32_t*)src,
                                     (__attribute__((address_space(3))) uint32_t*)dst, 16, 0, 0);
  }
  __builtin_amdgcn_sched_barrier(0);   // pin issue order: glds first, B loads after

  // ---- B ring prologue (tile 0): panel = colblk*32 + j*16 + w*4 + n,
  //      8192 B per panel; ks = 0,1 in flight (8 loads) ----
  const char* pb0 = (const char*)vpk + (size_t)(colblk * 32 + w * 4) * 8192 + lane * 16;
  const char* pb1 = pb0 + 16 * 8192;   // tile 1 base (+256 cols = 16 panels)

  short8 S[2][4];
  #pragma unroll
  for (int s = 0; s < 2; ++s)
    #pragma unroll
    for (int n = 0; n < 4; ++n)
      S[s][n] = *(const short8*)(pb0 + n * 8192 + s * 1024);

  // wait ONLY the 8 A-glds (oldest 8 of 16 outstanding); B loads stay in flight
  asm volatile("s_waitcnt vmcnt(8)" ::: "memory");
  __builtin_amdgcn_s_barrier();
  asm volatile("" ::: "memory");

  #pragma unroll
  for (int j = 0; j < 2; ++j) {
    const char* pb = (j == 0) ? pb0 : pb1;

    f32x4 acc[4][4];
    #pragma unroll
    for (int m = 0; m < 4; ++m)
      #pragma unroll
      for (int n = 0; n < 4; ++n)
        #pragma unroll
        for (int q = 0; q < 4; ++q)
          acc[m][n][q] = 0.0f;

    // ---- K loop: 8 static steps, no barriers. 2-deep ring (slot ks&1,
    //      refilled for ks+2); af loaded 2 fragments at a time. ----
    #pragma unroll
    for (int ks = 0; ks < 8; ++ks) {
      short8 af0 = *(const short8*)((const char*)As + (0 * 8 + ks) * 1024 + lane * 16);
      short8 af1 = *(const short8*)((const char*)As + (1 * 8 + ks) * 1024 + lane * 16);
      __builtin_amdgcn_s_setprio(1);
      #pragma unroll
      for (int n = 0; n < 4; ++n) {
        acc[0][n] = __builtin_amdgcn_mfma_f32_16x16x32_bf16(af0, S[ks & 1][n], acc[0][n], 0, 0, 0);
        acc[1][n] = __builtin_amdgcn_mfma_f32_16x16x32_bf16(af1, S[ks & 1][n], acc[1][n], 0, 0, 0);
      }
      __builtin_amdgcn_s_setprio(0);
      af0 = *(const short8*)((const char*)As + (2 * 8 + ks) * 1024 + lane * 16);
      af1 = *(const short8*)((const char*)As + (3 * 8 + ks) * 1024 + lane * 16);
      __builtin_amdgcn_s_setprio(1);
      #pragma unroll
      for (int n = 0; n < 4; ++n) {
        acc[2][n] = __builtin_amdgcn_mfma_f32_16x16x32_bf16(af0, S[ks & 1][n], acc[2][n], 0, 0, 0);
        acc[3][n] = __builtin_amdgcn_mfma_f32_16x16x32_bf16(af1, S[ks & 1][n], acc[3][n], 0, 0, 0);
      }
      __builtin_amdgcn_s_setprio(0);
      if (ks < 6) {                              // refill consumed slot for ks+2
        #pragma unroll
        for (int n = 0; n < 4; ++n)
          S[ks & 1][n] = *(const short8*)(pb + n * 8192 + (ks + 2) * 1024);
      }
    }

    // ---- refill ring for tile 1 NOW (S is dead); hides under the epilogue ----
    if (j == 0) {
      #pragma unroll
      for (int s = 0; s < 2; ++s)
        #pragma unroll
        for (int n = 0; n < 4; ++n)
          S[s][n] = *(const short8*)(pb1 + n * 8192 + s * 1024);
    }

    // ---- tile-j epilogue: PURE VALU/LDS (no vmem -> doesn't block S fill).
    // E = exp2(acc); rows -> rowsum LDS (owner-lane add), cols -> colsum LDS.
    // C/D layout: col = n*16 + lo16, row = m*16 + q4*4 + g.
    float colpart[4] = {0.f, 0.f, 0.f, 0.f};
    float rp[4][4];
    #pragma unroll
    for (int m = 0; m < 4; ++m)
      #pragma unroll
      for (int g = 0; g < 4; ++g)
        rp[m][g] = 0.0f;

    #pragma unroll
    for (int m = 0; m < 4; ++m)
      #pragma unroll
      for (int n = 0; n < 4; ++n)
        #pragma unroll
        for (int g = 0; g < 4; ++g) {
          float ev = __builtin_amdgcn_exp2f(acc[m][n][g]);
          rp[m][g] += ev;
          colpart[n] += ev;
        }

    #pragma unroll
    for (int m = 0; m < 4; ++m)
      #pragma unroll
      for (int g = 0; g < 4; ++g) {
        float rs = rp[m][g];
        rs += __shfl_xor(rs, 1);
        rs += __shfl_xor(rs, 2);
        rs += __shfl_xor(rs, 4);
        rs += __shfl_xor(rs, 8);
        if (lo16 == m * 4 + g) {
          int r = m * 16 + q4 * 4 + g;
          if (j == 0) rowsum[w][r] = rs;
          else        rowsum[w][r] += rs;          // same owner lane, no race
        }
      }

    #pragma unroll
    for (int n = 0; n < 4; ++n) {
      float cs = colpart[n];
      cs += __shfl_xor(cs, 16);
      cs += __shfl_xor(cs, 32);
      if (q4 == n) {
        colsum[j * 256 + w * 64 + n * 16 + lo16] = cs;   // written exactly once
      }
    }
  }

  __syncthreads();

  // ---- tail: all global atomics in one dependent-free burst ----
  atomicAdd(&out[NB + colblk * 512 + tid], colsum[tid]);
  atomicAdd(&out[NB + colblk * 512 + 256 + tid], colsum[256 + tid]);
  if (tid < 64) {
    float s = rowsum[0][tid] + rowsum[1][tid] + rowsum[2][tid] + rowsum[3][tid];
    atomicAdd(&out[rowblk * 64 + tid], s);
  }
}

extern "C" void kernel_launch(void* const* d_in, const int* in_sizes, int n_in,
                              void* d_out, int out_size, void* d_ws, size_t ws_size,
                              hipStream_t stream) {
  const float* e = (const float*)d_in[0];
  const float* v = (const float*)d_in[1];
  float* out = (float*)d_out;
  unsigned short* apk = (unsigned short*)d_ws;                 // 4 MiB packed e
  unsigned short* vpk = apk + (size_t)NB * DK;                 // 4 MiB packed v
  hipLaunchKernelGGL(normpack_kernel, dim3((2 * NB) / 4), dim3(256), 0, stream, e, v, apk, vpk, out);
  hipLaunchKernelGGL(score_kernel, dim3(2048), dim3(256), 0, stream, apk, vpk, out);
}

// Round 24
// 55.741 us; speedup vs baseline: 1.0189x; 1.0189x over previous
//
#include <hip/hip_runtime.h>
#include <hip/hip_bf16.h>
#include <stdint.h>

#define NB 8192
#define DK 256
// gamma * log2(e): epilogue uses native exp2
#define GSCALE 14.426950408889634f

typedef short short8 __attribute__((ext_vector_type(8)));
typedef float f32x4 __attribute__((ext_vector_type(4)));

__device__ __forceinline__ unsigned short f32_to_bf16(float f) {
  uint32_t u = __builtin_bit_cast(uint32_t, f);
  u += 0x7FFFu + ((u >> 16) & 1u);   // RNE
  return (unsigned short)(u >> 16);
}

// Normalize (gamma*log2e folded into e side) AND write in PACKED MFMA-fragment
// layout (16x16x32 shape): fragment (row-panel p = r>>4, ks = k>>5) is a
// contiguous 1-KB chunk; lane l owns bytes l*16..+16.
// packed_byte(r,k) = (r>>4)*8192 + (k>>5)*1024 + ((k>>3)&3)*256 + (r&15)*16 + (k&7)*2.
// Blocks 0..15 also zero d_out (replaces hipMemsetAsync).
__global__ __launch_bounds__(256) void normpack_kernel(const float* __restrict__ e,
                                                       const float* __restrict__ v,
                                                       unsigned short* __restrict__ apk,
                                                       unsigned short* __restrict__ vpk,
                                                       float* __restrict__ out) {
  if (blockIdx.x < 16) {
    float4 z = {0.f, 0.f, 0.f, 0.f};
    reinterpret_cast<float4*>(out)[blockIdx.x * 256 + threadIdx.x] = z;
  }
  int wave = threadIdx.x >> 6;
  int lane = threadIdx.x & 63;
  int row = blockIdx.x * 4 + wave;          // 0..16383
  const float* src;
  unsigned short* dstbase;
  float mul;
  if (row < NB) {
    src = e + (size_t)row * DK; dstbase = apk; mul = GSCALE;
  } else {
    row -= NB;
    src = v + (size_t)row * DK; dstbase = vpk; mul = 1.0f;
  }
  float4 x = reinterpret_cast<const float4*>(src)[lane];   // k = 4*lane .. +3
  float ss = x.x * x.x + x.y * x.y + x.z * x.z + x.w * x.w;
  #pragma unroll
  for (int off = 32; off >= 1; off >>= 1) ss += __shfl_xor(ss, off);
  float s = mul / fmaxf(sqrtf(ss), 1e-8f);
  ushort4 o;
  o.x = f32_to_bf16(x.x * s);
  o.y = f32_to_bf16(x.y * s);
  o.z = f32_to_bf16(x.z * s);
  o.w = f32_to_bf16(x.w * s);
  size_t off = (size_t)(row >> 4) * 8192 + (size_t)(lane >> 3) * 1024 +
               ((lane >> 1) & 3) * 256 + (row & 15) * 16 + (lane & 1) * 8;
  *reinterpret_cast<ushort4*>((char*)dstbase + off) = o;
}

// FINAL: exact R19/R22 configuration -- the session's verified best
// (55.8-56.0us total, reproduced twice). Core: 16x16x32 MFMA, packed operand
// fragments (LDS reads conflict-free by construction, B loads coalesced
// 1-KB), 64x512 block (2 sequential col-tiles), 4 waves, B register ring
// depth 3 with per-tile re-init (every deviation -- dynamic rings, cross-
// tile carries, forced occupancy caps, epilogue restructures, interior reg
// cuts -- spilled or regressed: R11/R12/R15/R17/R20/R21/R23), counted
// vmcnt(12) prologue (B loads fly through the barrier), setprio around the
// MFMA cluster, no in-loop barriers, pure-VALU/LDS per-tile epilogue with
// tile-1 ring fill hidden under it, all global atomics in one tail burst.
__global__ __launch_bounds__(256, 3) void score_kernel(const unsigned short* __restrict__ apk,
                                                       const unsigned short* __restrict__ vpk,
                                                       float* __restrict__ out) {
  __shared__ unsigned short As[16384];      // 32 KB packed A panel
  __shared__ float colsum[512];             // 2 KB
  __shared__ float rowsum[4][64];           // 1 KB

  const int tid = threadIdx.x;
  const int w = tid >> 6;          // 0..3 (64-col group within each tile)
  const int lane = tid & 63;
  const int lo16 = lane & 15;
  const int q4 = lane >> 4;        // 0..3

  // 2048 blocks: xcd = id&7; 2 colblks per XCD -> B hot-set 512 KB, L2-resident;
  // consecutive t walk rowblks within a colblk (A panel L2-reused).
  int id = blockIdx.x;
  int xcd = id & 7;
  int t = id >> 3;                      // 0..255
  int colblk = (xcd << 1) | (t & 1);    // 0..15  (512-col strip)
  int rowblk = t >> 1;                  // 0..127 (64-row panel)

  // ---- Stage A panel: 32 KB, pure linear copy of packed fragments ----
  const char* aP = (const char*)apk + (size_t)rowblk * 32768;
  #pragma unroll
  for (int u = 0; u < 8; ++u) {
    int chunk = w * 8 + u;                     // 0..31 (1-KB fragments)
    const char* src = aP + chunk * 1024 + lane * 16;
    unsigned short* dst = &As[chunk * 512];
    __builtin_amdgcn_global_load_lds((const __attribute__((address_space(1))) uint32_t*)src,
                                     (__attribute__((address_space(3))) uint32_t*)dst, 16, 0, 0);
  }
  __builtin_amdgcn_sched_barrier(0);   // pin issue order: glds first, B loads after

  // ---- B ring prologue (tile 0): wave's 4 col-panels, ks = 0,1,2 in flight ----
  // Tile j cols: colblk*512 + j*256 + w*64 + n*16; panel = col>>4
  //            = colblk*32 + j*16 + w*4 + n   (8192 B per panel).
  const char* pb0 = (const char*)vpk + (size_t)(colblk * 32 + w * 4) * 8192 + lane * 16;
  const char* pb1 = pb0 + 16 * 8192;   // tile 1 base (+256 cols = 16 panels)

  short8 S[3][4];
  #pragma unroll
  for (int s = 0; s < 3; ++s)
    #pragma unroll
    for (int n = 0; n < 4; ++n)
      S[s][n] = *(const short8*)(pb0 + n * 8192 + s * 1024);

  // wait ONLY the 8 A-glds (oldest 8 of 20 outstanding); B loads stay in flight
  asm volatile("s_waitcnt vmcnt(12)" ::: "memory");
  __builtin_amdgcn_s_barrier();
  asm volatile("" ::: "memory");

  #pragma unroll
  for (int j = 0; j < 2; ++j) {
    const char* pb = (j == 0) ? pb0 : pb1;

    f32x4 acc[4][4];
    #pragma unroll
    for (int m = 0; m < 4; ++m)
      #pragma unroll
      for (int n = 0; n < 4; ++n)
        #pragma unroll
        for (int q = 0; q < 4; ++q)
          acc[m][n][q] = 0.0f;

    // ---- K loop: 8 static steps, no barriers. 3-deep ring: step ks consumes
    //      S[ks%3]; refilled for step ks+3. ----
    #pragma unroll
    for (int ks = 0; ks < 8; ++ks) {
      short8 af[4];
      #pragma unroll
      for (int m = 0; m < 4; ++m)
        af[m] = *(const short8*)((const char*)As + (m * 8 + ks) * 1024 + lane * 16);
      __builtin_amdgcn_s_setprio(1);
      #pragma unroll
      for (int n = 0; n < 4; ++n)
        #pragma unroll
        for (int m = 0; m < 4; ++m)
          acc[m][n] = __builtin_amdgcn_mfma_f32_16x16x32_bf16(af[m], S[ks % 3][n], acc[m][n], 0, 0, 0);
      __builtin_amdgcn_s_setprio(0);
      if (ks < 5) {                              // refill consumed slot for ks+3
        #pragma unroll
        for (int n = 0; n < 4; ++n)
          S[ks % 3][n] = *(const short8*)(pb + n * 8192 + (ks + 3) * 1024);
      }
    }

    // ---- refill ring for tile 1 NOW (S is dead); hides under the epilogue ----
    if (j == 0) {
      #pragma unroll
      for (int s = 0; s < 3; ++s)
        #pragma unroll
        for (int n = 0; n < 4; ++n)
          S[s][n] = *(const short8*)(pb1 + n * 8192 + s * 1024);
    }

    // ---- tile-j epilogue: PURE VALU/LDS (no vmem -> doesn't block S fill).
    // E = exp2(acc); rows -> rowsum LDS (owner-lane add), cols -> colsum LDS.
    // C/D layout: col = n*16 + lo16, row = m*16 + q4*4 + g.
    float colpart[4] = {0.f, 0.f, 0.f, 0.f};
    float rp[4][4];
    #pragma unroll
    for (int m = 0; m < 4; ++m)
      #pragma unroll
      for (int g = 0; g < 4; ++g)
        rp[m][g] = 0.0f;

    #pragma unroll
    for (int m = 0; m < 4; ++m)
      #pragma unroll
      for (int n = 0; n < 4; ++n)
        #pragma unroll
        for (int g = 0; g < 4; ++g) {
          float ev = __builtin_amdgcn_exp2f(acc[m][n][g]);
          rp[m][g] += ev;
          colpart[n] += ev;
        }

    #pragma unroll
    for (int m = 0; m < 4; ++m)
      #pragma unroll
      for (int g = 0; g < 4; ++g) {
        float rs = rp[m][g];
        rs += __shfl_xor(rs, 1);
        rs += __shfl_xor(rs, 2);
        rs += __shfl_xor(rs, 4);
        rs += __shfl_xor(rs, 8);
        if (lo16 == m * 4 + g) {
          int r = m * 16 + q4 * 4 + g;
          if (j == 0) rowsum[w][r] = rs;
          else        rowsum[w][r] += rs;          // same owner lane, no race
        }
      }

    #pragma unroll
    for (int n = 0; n < 4; ++n) {
      float cs = colpart[n];
      cs += __shfl_xor(cs, 16);
      cs += __shfl_xor(cs, 32);
      if (q4 == n) {
        colsum[j * 256 + w * 64 + n * 16 + lo16] = cs;   // written exactly once
      }
    }
  }

  __syncthreads();

  // ---- tail: all global atomics in one dependent-free burst ----
  atomicAdd(&out[NB + colblk * 512 + tid], colsum[tid]);
  atomicAdd(&out[NB + colblk * 512 + 256 + tid], colsum[256 + tid]);
  if (tid < 64) {
    float s = rowsum[0][tid] + rowsum[1][tid] + rowsum[2][tid] + rowsum[3][tid];
    atomicAdd(&out[rowblk * 64 + tid], s);
  }
}

extern "C" void kernel_launch(void* const* d_in, const int* in_sizes, int n_in,
                              void* d_out, int out_size, void* d_ws, size_t ws_size,
                              hipStream_t stream) {
  const float* e = (const float*)d_in[0];
  const float* v = (const float*)d_in[1];
  float* out = (float*)d_out;
  unsigned short* apk = (unsigned short*)d_ws;                 // 4 MiB packed e
  unsigned short* vpk = apk + (size_t)NB * DK;                 // 4 MiB packed v
  hipLaunchKernelGGL(normpack_kernel, dim3((2 * NB) / 4), dim3(256), 0, stream, e, v, apk, vpk, out);
  hipLaunchKernelGGL(score_kernel, dim3(2048), dim3(256), 0, stream, apk, vpk, out);
}